// Round 17
// baseline (18.275 us; speedup 1.0000x reference)
//
#include <hip/hip_runtime.h>
#include <math.h>

#define NB   512

typedef __attribute__((ext_vector_type(8))) __bf16 bf16x8;
typedef __attribute__((ext_vector_type(4))) float  f32x4;

__device__ __forceinline__ float fast_rcp(float x) { return __builtin_amdgcn_rcpf(x); }
__device__ __forceinline__ float fast_tanh(float x) {
    float e = __expf(2.0f * x);
    return 1.0f - 2.0f * fast_rcp(e + 1.0f);
}
__device__ __forceinline__ float fast_sigmoid(float x) {
    return fast_rcp(1.0f + __expf(-x));
}
__device__ __forceinline__ unsigned pack_bf16(float a, float b) {
    unsigned short ux = __builtin_bit_cast(unsigned short, (__bf16)a);
    unsigned short uy = __builtin_bit_cast(unsigned short, (__bf16)b);
    return (unsigned)ux | ((unsigned)uy << 16);
}
__device__ __forceinline__ float bf16_res(float v) {   // v - bf16(v)
    return v - (float)(__bf16)v;
}

__global__ __launch_bounds__(512, 4)
void cga_fused(const float* __restrict__ x,
               const float* __restrict__ A_static,
               const float* __restrict__ w1, const float* __restrict__ b1,
               const float* __restrict__ w2, const float* __restrict__ b2,
               const float* __restrict__ w3, const float* __restrict__ b3,
               const float* __restrict__ diff_w, const float* __restrict__ diff_b,
               const float* __restrict__ edge_w, const float* __restrict__ edge_b,
               const float* __restrict__ att_w, const float* __restrict__ att_b,
               const float* __restrict__ cc1_w, const float* __restrict__ cc1_b,
               const float* __restrict__ bn_g, const float* __restrict__ bn_b,
               const float* __restrict__ bn_m, const float* __restrict__ bn_v,
               const float* __restrict__ cc2_w, const float* __restrict__ cc2_b,
               const float* __restrict__ cs_w, const float* __restrict__ cs_b,
               const float* __restrict__ alpha_p,
               float* __restrict__ out)
{
    const int b = blockIdx.x;
    const int t = threadIdx.x;
    const int c = t & 63;   // lane
    const int w = t >> 6;   // wave 0..7

    // Bmats: j=0..7 Q_m as B[n=v][k=u]; j=8..15 P_m as B[n=u][k=v]; j=16 A_static [n=u][k=v].
    // Within every 32x32 matrix ROW, 16B column-blocks are XOR-swizzled: blk' = blk ^ (row&3)
    // (bank-conflict fix: 8-way -> 2-way on the A/B-phase b128 reads).
    // Before P2, Bmats elems [0..5119] alias wA hi [80][64] (XOR-swizzled fragments),
    // [5120..10239] wA lo. A_static block (elems 16384..) untouched by staging.
    __shared__ __align__(16) __bf16 Bmats[17 * 32 * 32];   // 34816 B
    __shared__ __align__(16) __bf16 x3bf[64 * 32];         // A-operand [c][k=v], blk-swizzled
    __shared__ __align__(16) __bf16 xT[2 * 32 * 72];       // x^T hi/lo planes [v][cin], stride 72
    __shared__ float x1s[200], x2s[200];
    __shared__ __align__(16) float xatt[1600];
    __shared__ __align__(16) float gcnp[1600];
    __shared__ float att_wT[512], edge_wT[512];            // [j][c], edge pre-scaled by alpha
    __shared__ float S3s[64], catt[64], satt[32];
    __shared__ float xmean[64], hbuf[32], csct[64];

    const float alpha = alpha_p[0];
    const float* xb = x + (size_t)b * 1600;
    __bf16* const xThi = xT;
    __bf16* const xTlo = xT + 32 * 72;

    // ===== x preload: thread t<400 owns elements 4t..4t+3 (one float4) =====
    float4 xq = {0.f, 0.f, 0.f, 0.f};
    if (t < 400) xq = *(const float4*)&xb[4 * t];

    // ===== stage: x -> transposed hi/lo, wA hi/lo (swizzled), misc =====
    {
        if (t < 400) {
            #pragma unroll
            for (int j = 0; j < 4; ++j) {
                int i = 4 * t + j;
                int cin = i / 25, v = i - cin * 25;
                float f = (&xq.x)[j];
                __bf16 h = (__bf16)f;
                xThi[v * 72 + cin] = h;
                xTlo[v * 72 + cin] = (__bf16)(f - (float)h);
            }
        }
        #pragma unroll 1
        for (int i = t; i < 1008; i += 512) {           // zero pad rows v=25..31, both planes
            int p = (i >= 504), r = i - p * 504;
            (p ? xTlo : xThi)[25 * 72 + r] = (__bf16)0.f;
        }
        // wA fragments, XOR-swizzled: dword sw = i ^ (((i>>5)&7)<<2)
        unsigned* wA32   = (unsigned*)Bmats;
        unsigned* wAlo32 = wA32 + 2560;
        #pragma unroll 1
        for (int i = t; i < 2048; i += 512) {
            float2 wv = *(const float2*)&w3[2 * i];
            int sw = i ^ (((i >> 5) & 7) << 2);
            wA32[sw]   = pack_bf16(wv.x, wv.y);
            wAlo32[sw] = pack_bf16(bf16_res(wv.x), bf16_res(wv.y));
        }
        {   // w1 -> rows 64-71, w2 -> rows 72-79 (256 u32 each)
            int which = t >> 8, j = t & 255;
            const float* wsrc = which ? w2 : w1;
            float2 wv = *(const float2*)&wsrc[2 * j];
            int i2 = 2048 + t;
            int sw = i2 ^ (((i2 >> 5) & 7) << 2);
            wA32[sw]   = pack_bf16(wv.x, wv.y);
            wAlo32[sw] = pack_bf16(bf16_res(wv.x), bf16_res(wv.y));
        }
        unsigned* x3b32 = (unsigned*)x3bf;
        #pragma unroll 1
        for (int i = t; i < 1024; i += 512) x3b32[i] = 0u;
        {   // att_wT[j][c], edge_wT[j][c] (alpha folded)
            int j = t >> 6;
            att_wT [j * 64 + c] = att_w [c * 8 + j];
            edge_wT[j * 64 + c] = alpha * edge_w[c * 8 + j];
        }
        {   // A_static -> Bmats[16][n=u][k=v], zero-padded, blk-swizzled
            int n = t >> 4, p = t & 15;         // p = dword (2 cols)
            int k0 = 2 * p, k1 = k0 + 1;
            float a0 = (n < 25 && k0 < 25) ? A_static[n * 25 + k0] : 0.0f;
            float a1 = (n < 25 && k1 < 25) ? A_static[n * 25 + k1] : 0.0f;
            int pn = (((p >> 2) ^ (n & 3)) << 2) | (p & 3);
            ((unsigned*)Bmats)[16 * 512 + n * 16 + pn] = pack_bf16(a0, a1);
        }
    }
    __syncthreads();

    // ===== P1 (split-bf16 MFMA): [x3; x1; x2] = wA(80x64) @ x(64x25) =====
    {
        const int ln = c & 15, kq = c >> 4;
        #pragma unroll 1
        for (int pass = 0; pass < 2; ++pass) {
            const int jb = pass ? (w + 8) : w;
            if (jb <= 9) {
                const int nt = (jb >= 5) ? 1 : 0;
                const int mt = jb - nt * 5;
                const int arow = mt * 16 + ln;
                const int brow = nt * 16 + ln;
                const int r7 = arow & 7;
                const __bf16* hiB = Bmats        + arow * 64;
                const __bf16* loB = Bmats + 5120 + arow * 64;
                bf16x8 ah0 = *(const bf16x8*)(hiB + (((kq    ) ^ r7) << 3));
                bf16x8 ah1 = *(const bf16x8*)(hiB + (((kq + 4) ^ r7) << 3));
                bf16x8 al0 = *(const bf16x8*)(loB + (((kq    ) ^ r7) << 3));
                bf16x8 al1 = *(const bf16x8*)(loB + (((kq + 4) ^ r7) << 3));
                bf16x8 bh0 = *(const bf16x8*)&xThi[brow * 72 + kq * 8];
                bf16x8 bh1 = *(const bf16x8*)&xThi[brow * 72 + 32 + kq * 8];
                bf16x8 bl0 = *(const bf16x8*)&xTlo[brow * 72 + kq * 8];
                bf16x8 bl1 = *(const bf16x8*)&xTlo[brow * 72 + 32 + kq * 8];
                f32x4 accA = {0.f, 0.f, 0.f, 0.f};     // split chains: 2 + 4
                f32x4 accB = {0.f, 0.f, 0.f, 0.f};
                accA = __builtin_amdgcn_mfma_f32_16x16x32_bf16(ah0, bh0, accA, 0, 0, 0);
                accA = __builtin_amdgcn_mfma_f32_16x16x32_bf16(ah1, bh1, accA, 0, 0, 0);
                accB = __builtin_amdgcn_mfma_f32_16x16x32_bf16(ah0, bl0, accB, 0, 0, 0);
                accB = __builtin_amdgcn_mfma_f32_16x16x32_bf16(ah1, bl1, accB, 0, 0, 0);
                accB = __builtin_amdgcn_mfma_f32_16x16x32_bf16(al0, bh0, accB, 0, 0, 0);
                accB = __builtin_amdgcn_mfma_f32_16x16x32_bf16(al1, bh1, accB, 0, 0, 0);
                f32x4 acc = accA + accB;
                const int colv = nt * 16 + ln;
                if (colv < 25) {
                    if (mt < 4) {
                        const int cpos = (colv >> 3), crem = colv & 7;
                        #pragma unroll
                        for (int r = 0; r < 4; ++r) {
                            int cc = mt * 16 + kq * 4 + r;
                            float val = acc[r] + b3[cc];
                            x3bf[cc * 32 + (((cpos ^ (cc & 3)) << 3) | crem)] = (__bf16)val;
                        }
                    } else {
                        #pragma unroll
                        for (int r = 0; r < 4; ++r) {
                            int row16 = kq * 4 + r;
                            int which = row16 >> 3, m = row16 & 7;
                            float val = acc[r] + (which ? b2[m] : b1[m]);
                            (which ? x2s : x1s)[m * 25 + colv] = val;
                        }
                    }
                }
            }
        }
    }
    __syncthreads();

    // ===== P2: wave-uniform m = t>>6; 4 rows x 1 col-quad of Q_m and P_m; swizzled stores =====
    {
        const int m  = t >> 6;          // wave-uniform
        const int l  = t & 63;
        const int ab = l >> 3;          // row base (0..7)
        const int q8 = l & 7;           // col quad
        const float dw0 = diff_w[2 * m], dw1 = diff_w[2 * m + 1], db = diff_b[m];
        const float* rowA; const float* colA; int j0;
        if (m < 4) { j0 = 2 * m;     rowA = x1s; colA = x2s; }
        else       { j0 = 2 * m - 8; rowA = x2s; colA = x1s; }
        // hoisted column terms (loaded once)
        float x1c[4], csum[4];
        #pragma unroll
        for (int e = 0; e < 4; ++e) {
            int vv = 4 * q8 + e;
            if (vv < 25) {
                x1c[e]  = x1s[m * 25 + vv] * 0.2f;
                csum[e] = dw0 * colA[j0 * 25 + vv] + dw1 * colA[(j0 + 1) * 25 + vv];
            } else { x1c[e] = 0.f; csum[e] = 0.f; }
        }
        const int blk = q8 >> 1, half = q8 & 1;
        #pragma unroll
        for (int k = 0; k < 4; ++k) {
            int a = ab + 8 * k;         // row 0..31
            float qv[4] = {0.f, 0.f, 0.f, 0.f};
            float pv[4] = {0.f, 0.f, 0.f, 0.f};
            if (a < 25) {
                float x2a = x2s[m * 25 + a];
                float t0  = dw0 * rowA[j0 * 25 + a] + dw1 * rowA[(j0 + 1) * 25 + a] + db;
                #pragma unroll
                for (int e = 0; e < 4; ++e) {
                    if (4 * q8 + e < 25) {
                        qv[e] = fast_tanh(x1c[e] * x2a);
                        pv[e] = fast_tanh(t0 - csum[e]);
                    }
                }
            }
            unsigned long long qw = (unsigned long long)pack_bf16(qv[0], qv[1])
                                  | ((unsigned long long)pack_bf16(qv[2], qv[3]) << 32);
            unsigned long long pw = (unsigned long long)pack_bf16(pv[0], pv[1])
                                  | ((unsigned long long)pack_bf16(pv[2], pv[3]) << 32);
            int pos = ((blk ^ (a & 3)) << 2) + (half << 1);   // swizzled dword offset in row
            *(unsigned long long*)&((unsigned*)Bmats)[(m * 32 + a) * 16 + pos]       = qw;
            *(unsigned long long*)&((unsigned*)Bmats)[((8 + m) * 32 + a) * 16 + pos] = pw;
        }
    }
    if (t < 64) {   // S3: whole-row sum of x3bf (block permutation is sum-invariant)
        const bf16x8* xr = (const bf16x8*)&x3bf[t * 32];
        float s = 0.0f;
        #pragma unroll
        for (int q = 0; q < 4; ++q) {
            bf16x8 vq = xr[q];
            #pragma unroll
            for (int e = 0; e < 8; ++e) s += (float)vq[e];
        }
        S3s[t] = s;
    }
    __syncthreads();

    // ===== A/B MFMA: waves 0-3 -> xatt (j 0..7), waves 4-7 -> gcnp (j 8..16) =====
    {
        const int ln = c & 15, kq = c >> 4;
        const int grp = w >> 2;
        const int mt  = w & 3;
        const int arow = mt * 16 + ln;
        const int swk = ((kq ^ (ln & 3)) << 3);   // (arow&3 == ln&3, (16+ln)&3 == ln&3)

        const bf16x8 araw = *(const bf16x8*)&x3bf[arow * 32 + swk];
        float av[8];
        #pragma unroll
        for (int e = 0; e < 8; ++e) av[e] = (float)araw[e];

        f32x4 acc0e = {0.f,0.f,0.f,0.f}, acc0o = {0.f,0.f,0.f,0.f};
        f32x4 acc1e = {0.f,0.f,0.f,0.f}, acc1o = {0.f,0.f,0.f,0.f};
        const float* scT = grp ? edge_wT : att_wT;
        const int jbase = grp ? 8 : 0;

        #pragma unroll
        for (int j = 0; j < 8; ++j) {
            float sj = scT[j * 64 + arow];
            bf16x8 aj;
            #pragma unroll
            for (int e = 0; e < 8; ++e) aj[e] = (__bf16)(av[e] * sj);
            const __bf16* bj = &Bmats[(jbase + j) * 1024];
            bf16x8 b0 = *(const bf16x8*)(bj + ln * 32 + swk);
            bf16x8 b1 = *(const bf16x8*)(bj + (16 + ln) * 32 + swk);
            if (j & 1) {
                acc0o = __builtin_amdgcn_mfma_f32_16x16x32_bf16(aj, b0, acc0o, 0, 0, 0);
                acc1o = __builtin_amdgcn_mfma_f32_16x16x32_bf16(aj, b1, acc1o, 0, 0, 0);
            } else {
                acc0e = __builtin_amdgcn_mfma_f32_16x16x32_bf16(aj, b0, acc0e, 0, 0, 0);
                acc1e = __builtin_amdgcn_mfma_f32_16x16x32_bf16(aj, b1, acc1e, 0, 0, 0);
            }
        }
        if (grp) {  // + A_static @ x3 (unit scale)
            const __bf16* bj = &Bmats[16 * 1024];
            bf16x8 b0 = *(const bf16x8*)(bj + ln * 32 + swk);
            bf16x8 b1 = *(const bf16x8*)(bj + (16 + ln) * 32 + swk);
            acc0e = __builtin_amdgcn_mfma_f32_16x16x32_bf16(araw, b0, acc0e, 0, 0, 0);
            acc1e = __builtin_amdgcn_mfma_f32_16x16x32_bf16(araw, b1, acc1e, 0, 0, 0);
        }
        f32x4 acc0 = acc0e + acc0o;
        f32x4 acc1 = acc1e + acc1o;
        float* dstArr = grp ? gcnp : xatt;
        #pragma unroll
        for (int r = 0; r < 4; ++r) {
            int row = mt * 16 + kq * 4 + r;
            float bias = grp ? (alpha * edge_b[row] * S3s[row])
                             : (att_b[row] * S3s[row]);
            dstArr[row * 25 + ln] = acc0[r] + bias;
            if (ln < 9) dstArr[row * 25 + 16 + ln] = acc1[r] + bias;
            if (!grp) {   // fold xmean: row-sum from accumulator registers
                float s = acc0[r] + ((ln < 9) ? acc1[r] : 0.0f);
                s += __shfl_xor(s, 1, 16);
                s += __shfl_xor(s, 2, 16);
                s += __shfl_xor(s, 4, 16);
                s += __shfl_xor(s, 8, 16);
                if (ln == 0) xmean[row] = (s + 25.0f * bias) * 0.04f;
            }
        }
    }
    __syncthreads();

    // ===== prefetch epilogue operands (float4 LDS reads; quad ownership) =====
    float4 g4 = {0.f, 0.f, 0.f, 0.f}, xa4 = {0.f, 0.f, 0.f, 0.f};
    if (t < 400) {
        g4  = *(const float4*)&gcnp[4 * t];
        xa4 = *(const float4*)&xatt[4 * t];
    }

    // ===== MLP stage B (parallel): h[i] = GELU(BN(cc1 @ xm)), 8 lanes per i =====
    if (t < 256) {
        int i = t >> 3, s = t & 7;
        float p = 0.0f;
        #pragma unroll
        for (int k = 0; k < 8; ++k)
            p += cc1_w[i * 64 + s + 8 * k] * xmean[s + 8 * k];
        p += __shfl_down(p, 4, 8);
        p += __shfl_down(p, 2, 8);
        p += __shfl_down(p, 1, 8);
        if (s == 0) {
            p += cc1_b[i];
            p = (p - bn_m[i]) * (bn_g[i] * rsqrtf(bn_v[i] + 1e-5f)) + bn_b[i];
            hbuf[i] = 0.5f * p * (1.0f + erff(p * 0.70710678118654752f));
        }
    }
    __syncthreads();

    // ===== MLP stage C (parallel): catt[c] = sigmoid(cc2 @ h), 4 lanes per c =====
    if (t < 256) {
        int cq = t >> 2, s = t & 3;
        float p = 0.0f;
        #pragma unroll
        for (int k = 0; k < 8; ++k)
            p += cc2_w[cq * 32 + s + 4 * k] * hbuf[s + 4 * k];
        p += __shfl_down(p, 2, 4);
        p += __shfl_down(p, 1, 4);
        if (s == 0) {
            float cv = fast_sigmoid(p + cc2_b[cq]);
            catt[cq] = cv;
            csct[cq] = cs_w[cq] * cv;
        }
    }
    __syncthreads();

    // ===== satt (t<200) overlapped with epilogue partials (t<400) =====
    float part[4];
    if (t < 400) {
        #pragma unroll
        for (int j = 0; j < 4; ++j) {
            int i = 4 * t + j;
            int cc = i / 25;
            part[j] = (&g4.x)[j] * catt[cc] + (&xq.x)[j];
        }
    }
    if (t < 200) {
        int v = t >> 3, s8 = t & 7;
        float p = 0.0f;
        #pragma unroll
        for (int k = 0; k < 8; ++k) {
            int cc = s8 + 8 * k;
            p += csct[cc] * gcnp[cc * 25 + v];
        }
        p += __shfl_down(p, 4, 8);
        p += __shfl_down(p, 2, 8);
        p += __shfl_down(p, 1, 8);
        if (s8 == 0) satt[v] = fast_sigmoid(p + cs_b[0]);
    }
    __syncthreads();

    // ===== out = part + xatt*satt (float4 global store) =====
    if (t < 400) {
        float4 o;
        #pragma unroll
        for (int j = 0; j < 4; ++j) {
            int i = 4 * t + j;
            int cc = i / 25, v = i - cc * 25;
            (&o.x)[j] = part[j] + (&xa4.x)[j] * satt[v];
        }
        *(float4*)&out[(size_t)b * 1600 + 4 * t] = o;
    }
}

extern "C" void kernel_launch(void* const* d_in, const int* in_sizes, int n_in,
                              void* d_out, int out_size, void* d_ws, size_t ws_size,
                              hipStream_t stream) {
    const float* x        = (const float*)d_in[0];
    const float* A_static = (const float*)d_in[1];
    const float* w1       = (const float*)d_in[2];
    const float* b1       = (const float*)d_in[3];
    const float* w2       = (const float*)d_in[4];
    const float* b2       = (const float*)d_in[5];
    const float* w3       = (const float*)d_in[6];
    const float* b3       = (const float*)d_in[7];
    const float* diff_w   = (const float*)d_in[8];
    const float* diff_b   = (const float*)d_in[9];
    const float* edge_w   = (const float*)d_in[10];
    const float* edge_b   = (const float*)d_in[11];
    const float* att_w    = (const float*)d_in[12];
    const float* att_b    = (const float*)d_in[13];
    const float* cc1_w    = (const float*)d_in[14];
    const float* cc1_b    = (const float*)d_in[15];
    const float* bn_g     = (const float*)d_in[16];
    const float* bn_b     = (const float*)d_in[17];
    const float* bn_m     = (const float*)d_in[18];
    const float* bn_v     = (const float*)d_in[19];
    const float* cc2_w    = (const float*)d_in[20];
    const float* cc2_b    = (const float*)d_in[21];
    const float* cs_w     = (const float*)d_in[22];
    const float* cs_b     = (const float*)d_in[23];
    const float* alpha    = (const float*)d_in[24];
    float* outp = (float*)d_out;

    cga_fused<<<NB, 512, 0, stream>>>(x, A_static, w1, b1, w2, b2, w3, b3,
                                      diff_w, diff_b, edge_w, edge_b,
                                      att_w, att_b, cc1_w, cc1_b,
                                      bn_g, bn_b, bn_m, bn_v,
                                      cc2_w, cc2_b, cs_w, cs_b, alpha, outp);
}

// Round 18
// 17.361 us; speedup vs baseline: 1.0527x; 1.0527x over previous
//
#include <hip/hip_runtime.h>
#include <math.h>

#define NB   512

typedef __attribute__((ext_vector_type(8))) __bf16 bf16x8;
typedef __attribute__((ext_vector_type(4))) float  f32x4;

__device__ __forceinline__ float fast_rcp(float x) { return __builtin_amdgcn_rcpf(x); }
__device__ __forceinline__ float fast_tanh(float x) {
    float e = __expf(2.0f * x);
    return 1.0f - 2.0f * fast_rcp(e + 1.0f);
}
__device__ __forceinline__ float fast_sigmoid(float x) {
    return fast_rcp(1.0f + __expf(-x));
}
__device__ __forceinline__ unsigned pack_bf16(float a, float b) {
    unsigned short ux = __builtin_bit_cast(unsigned short, (__bf16)a);
    unsigned short uy = __builtin_bit_cast(unsigned short, (__bf16)b);
    return (unsigned)ux | ((unsigned)uy << 16);
}
__device__ __forceinline__ float bf16_res(float v) {   // v - bf16(v)
    return v - (float)(__bf16)v;
}

__global__ __launch_bounds__(512, 4)
void cga_fused(const float* __restrict__ x,
               const float* __restrict__ A_static,
               const float* __restrict__ w1, const float* __restrict__ b1,
               const float* __restrict__ w2, const float* __restrict__ b2,
               const float* __restrict__ w3, const float* __restrict__ b3,
               const float* __restrict__ diff_w, const float* __restrict__ diff_b,
               const float* __restrict__ edge_w, const float* __restrict__ edge_b,
               const float* __restrict__ att_w, const float* __restrict__ att_b,
               const float* __restrict__ cc1_w, const float* __restrict__ cc1_b,
               const float* __restrict__ bn_g, const float* __restrict__ bn_b,
               const float* __restrict__ bn_m, const float* __restrict__ bn_v,
               const float* __restrict__ cc2_w, const float* __restrict__ cc2_b,
               const float* __restrict__ cs_w, const float* __restrict__ cs_b,
               const float* __restrict__ alpha_p,
               float* __restrict__ out)
{
    const int b = blockIdx.x;
    const int t = threadIdx.x;
    const int c = t & 63;   // lane
    const int w = t >> 6;   // wave 0..7

    // Bmats: j=0..7 Q_m as B[n=v][k=u]; j=8..15 P_m as B[n=u][k=v]; j=16 A_static [n=u][k=v].
    // Before P2, Bmats elems [0..5119] alias wA hi [80][64] (XOR-swizzled fragments),
    // [5120..10239] wA lo. A_static block (elems 16384..) untouched by staging.
    __shared__ __align__(16) __bf16 Bmats[17 * 32 * 32];   // 34816 B
    __shared__ __align__(16) __bf16 x3bf[64 * 32];         // A-operand of A/B phase [c][k=v]
    __shared__ __align__(16) __bf16 xT[2 * 32 * 72];       // x^T hi/lo planes [v][cin], stride 72
    __shared__ float x1s[200], x2s[200];
    __shared__ __align__(16) float xatt[1600];
    __shared__ __align__(16) float gcnp[1600];
    __shared__ float S3s[64], catt[64], satt[32];
    __shared__ float xmean[64], hbuf[32], csct[64];

    const float alpha = alpha_p[0];
    const float* xb = x + (size_t)b * 1600;
    __bf16* const xThi = xT;
    __bf16* const xTlo = xT + 32 * 72;

    // ===== x preload: thread t<400 owns elements 4t..4t+3 (one float4) =====
    float4 xq = {0.f, 0.f, 0.f, 0.f};
    if (t < 400) xq = *(const float4*)&xb[4 * t];

    // ===== stage: x -> transposed hi/lo, wA hi/lo (swizzled), misc =====
    {
        if (t < 400) {
            #pragma unroll
            for (int j = 0; j < 4; ++j) {
                int i = 4 * t + j;
                int cin = i / 25, v = i - cin * 25;
                float f = (&xq.x)[j];
                __bf16 h = (__bf16)f;
                xThi[v * 72 + cin] = h;
                xTlo[v * 72 + cin] = (__bf16)(f - (float)h);
            }
        }
        #pragma unroll 1
        for (int i = t; i < 1008; i += 512) {           // zero pad rows v=25..31, both planes
            int p = (i >= 504), r = i - p * 504;
            (p ? xTlo : xThi)[25 * 72 + r] = (__bf16)0.f;
        }
        // wA fragments, XOR-swizzled: dword sw = i ^ (((i>>5)&7)<<2)
        unsigned* wA32   = (unsigned*)Bmats;
        unsigned* wAlo32 = wA32 + 2560;
        #pragma unroll 1
        for (int i = t; i < 2048; i += 512) {
            float2 wv = *(const float2*)&w3[2 * i];
            int sw = i ^ (((i >> 5) & 7) << 2);
            wA32[sw]   = pack_bf16(wv.x, wv.y);
            wAlo32[sw] = pack_bf16(bf16_res(wv.x), bf16_res(wv.y));
        }
        {   // w1 -> rows 64-71, w2 -> rows 72-79 (256 u32 each)
            int which = t >> 8, j = t & 255;
            const float* wsrc = which ? w2 : w1;
            float2 wv = *(const float2*)&wsrc[2 * j];
            int i2 = 2048 + t;
            int sw = i2 ^ (((i2 >> 5) & 7) << 2);
            wA32[sw]   = pack_bf16(wv.x, wv.y);
            wAlo32[sw] = pack_bf16(bf16_res(wv.x), bf16_res(wv.y));
        }
        unsigned* x3b32 = (unsigned*)x3bf;
        #pragma unroll 1
        for (int i = t; i < 1024; i += 512) x3b32[i] = 0u;
        {   // A_static -> Bmats[16][n=u][k=v], zero-padded
            int n = t >> 4, p = t & 15;
            int k0 = 2 * p, k1 = k0 + 1;
            float a0 = (n < 25 && k0 < 25) ? A_static[n * 25 + k0] : 0.0f;
            float a1 = (n < 25 && k1 < 25) ? A_static[n * 25 + k1] : 0.0f;
            ((unsigned*)Bmats)[16 * 512 + n * 16 + p] = pack_bf16(a0, a1);
        }
    }
    __syncthreads();

    // ===== P1 (split-bf16 MFMA): [x3; x1; x2] = wA(80x64) @ x(64x25) =====
    {
        const int ln = c & 15, kq = c >> 4;
        #pragma unroll 1
        for (int pass = 0; pass < 2; ++pass) {
            const int jb = pass ? (w + 8) : w;
            if (jb <= 9) {
                const int nt = (jb >= 5) ? 1 : 0;
                const int mt = jb - nt * 5;
                const int arow = mt * 16 + ln;
                const int brow = nt * 16 + ln;
                const int r7 = arow & 7;
                const __bf16* hiB = Bmats        + arow * 64;
                const __bf16* loB = Bmats + 5120 + arow * 64;
                f32x4 acc = {0.f, 0.f, 0.f, 0.f};
                bf16x8 ah0 = *(const bf16x8*)(hiB + (((kq    ) ^ r7) << 3));
                bf16x8 ah1 = *(const bf16x8*)(hiB + (((kq + 4) ^ r7) << 3));
                bf16x8 al0 = *(const bf16x8*)(loB + (((kq    ) ^ r7) << 3));
                bf16x8 al1 = *(const bf16x8*)(loB + (((kq + 4) ^ r7) << 3));
                bf16x8 bh0 = *(const bf16x8*)&xThi[brow * 72 + kq * 8];
                bf16x8 bh1 = *(const bf16x8*)&xThi[brow * 72 + 32 + kq * 8];
                bf16x8 bl0 = *(const bf16x8*)&xTlo[brow * 72 + kq * 8];
                bf16x8 bl1 = *(const bf16x8*)&xTlo[brow * 72 + 32 + kq * 8];
                acc = __builtin_amdgcn_mfma_f32_16x16x32_bf16(ah0, bh0, acc, 0, 0, 0);
                acc = __builtin_amdgcn_mfma_f32_16x16x32_bf16(ah1, bh1, acc, 0, 0, 0);
                acc = __builtin_amdgcn_mfma_f32_16x16x32_bf16(ah0, bl0, acc, 0, 0, 0);
                acc = __builtin_amdgcn_mfma_f32_16x16x32_bf16(ah1, bl1, acc, 0, 0, 0);
                acc = __builtin_amdgcn_mfma_f32_16x16x32_bf16(al0, bh0, acc, 0, 0, 0);
                acc = __builtin_amdgcn_mfma_f32_16x16x32_bf16(al1, bh1, acc, 0, 0, 0);
                const int colv = nt * 16 + ln;
                if (colv < 25) {
                    if (mt < 4) {
                        #pragma unroll
                        for (int r = 0; r < 4; ++r) {
                            int cc = mt * 16 + kq * 4 + r;
                            float val = acc[r] + b3[cc];
                            x3bf[cc * 32 + colv] = (__bf16)val;
                        }
                    } else {
                        #pragma unroll
                        for (int r = 0; r < 4; ++r) {
                            int row16 = kq * 4 + r;
                            int which = row16 >> 3, m = row16 & 7;
                            float val = acc[r] + (which ? b2[m] : b1[m]);
                            (which ? x2s : x1s)[m * 25 + colv] = val;
                        }
                    }
                }
            }
        }
    }
    __syncthreads();

    // ===== P2: wave-uniform m = t>>6; thread owns 4 rows x 1 col-quad of Q_m and P_m =====
    {
        const int m  = t >> 6;          // wave-uniform
        const int l  = t & 63;
        const int ab = l >> 3;          // row base (0..7)
        const int q8 = l & 7;           // col quad
        const float dw0 = diff_w[2 * m], dw1 = diff_w[2 * m + 1], db = diff_b[m];
        const float* rowA; const float* colA; int j0;
        if (m < 4) { j0 = 2 * m;     rowA = x1s; colA = x2s; }
        else       { j0 = 2 * m - 8; rowA = x2s; colA = x1s; }
        // hoisted column terms (loaded once)
        float x1c[4], csum[4];
        #pragma unroll
        for (int e = 0; e < 4; ++e) {
            int vv = 4 * q8 + e;
            if (vv < 25) {
                x1c[e]  = x1s[m * 25 + vv] * 0.2f;
                csum[e] = dw0 * colA[j0 * 25 + vv] + dw1 * colA[(j0 + 1) * 25 + vv];
            } else { x1c[e] = 0.f; csum[e] = 0.f; }
        }
        #pragma unroll
        for (int k = 0; k < 4; ++k) {
            int a = ab + 8 * k;         // row 0..31
            float qv[4] = {0.f, 0.f, 0.f, 0.f};
            float pv[4] = {0.f, 0.f, 0.f, 0.f};
            if (a < 25) {
                float x2a = x2s[m * 25 + a];
                float t0  = dw0 * rowA[j0 * 25 + a] + dw1 * rowA[(j0 + 1) * 25 + a] + db;
                #pragma unroll
                for (int e = 0; e < 4; ++e) {
                    if (4 * q8 + e < 25) {
                        qv[e] = fast_tanh(x1c[e] * x2a);
                        pv[e] = fast_tanh(t0 - csum[e]);
                    }
                }
            }
            unsigned long long qw = (unsigned long long)pack_bf16(qv[0], qv[1])
                                  | ((unsigned long long)pack_bf16(qv[2], qv[3]) << 32);
            unsigned long long pw = (unsigned long long)pack_bf16(pv[0], pv[1])
                                  | ((unsigned long long)pack_bf16(pv[2], pv[3]) << 32);
            *(unsigned long long*)&((unsigned*)Bmats)[(m * 32 + a) * 16 + 2 * q8]       = qw;
            *(unsigned long long*)&((unsigned*)Bmats)[((8 + m) * 32 + a) * 16 + 2 * q8] = pw;
        }
    }
    if (t < 64) {               // S3 from zero-padded bf16 x3 row (vector reads)
        const bf16x8* xr = (const bf16x8*)&x3bf[t * 32];
        float s = 0.0f;
        #pragma unroll
        for (int q = 0; q < 4; ++q) {
            bf16x8 vq = xr[q];
            #pragma unroll
            for (int e = 0; e < 8; ++e) s += (float)vq[e];
        }
        S3s[t] = s;
    }
    __syncthreads();

    // ===== A/B MFMA: waves 0-3 -> xatt (j 0..7), waves 4-7 -> gcnp (j 8..16) =====
    {
        const int ln = c & 15, kq = c >> 4;
        const int grp = w >> 2;
        const int mt  = w & 3;
        const int arow = mt * 16 + ln;

        // per-lane scale row from GLOBAL (L2-hot), alpha folded — no LDS staging
        const float* wsel = grp ? edge_w : att_w;
        const float scl = grp ? alpha : 1.0f;
        float4 wv0 = *(const float4*)&wsel[arow * 8];
        float4 wv1 = *(const float4*)&wsel[arow * 8 + 4];
        float awv[8] = {wv0.x * scl, wv0.y * scl, wv0.z * scl, wv0.w * scl,
                        wv1.x * scl, wv1.y * scl, wv1.z * scl, wv1.w * scl};

        const bf16x8 araw = *(const bf16x8*)&x3bf[arow * 32 + kq * 8];
        float av[8];
        #pragma unroll
        for (int e = 0; e < 8; ++e) av[e] = (float)araw[e];

        f32x4 acc0 = {0.f, 0.f, 0.f, 0.f};
        f32x4 acc1 = {0.f, 0.f, 0.f, 0.f};
        const int jbase = grp ? 8 : 0;

        #pragma unroll
        for (int j = 0; j < 8; ++j) {
            float sj = awv[j];
            bf16x8 aj;
            #pragma unroll
            for (int e = 0; e < 8; ++e) aj[e] = (__bf16)(av[e] * sj);
            const __bf16* bb = &Bmats[(jbase + j) * 1024 + kq * 8];
            bf16x8 b0 = *(const bf16x8*)(bb + ln * 32);
            bf16x8 b1 = *(const bf16x8*)(bb + (16 + ln) * 32);
            acc0 = __builtin_amdgcn_mfma_f32_16x16x32_bf16(aj, b0, acc0, 0, 0, 0);
            acc1 = __builtin_amdgcn_mfma_f32_16x16x32_bf16(aj, b1, acc1, 0, 0, 0);
        }
        if (grp) {  // + A_static @ x3 (unit scale)
            const __bf16* bb = &Bmats[16 * 1024 + kq * 8];
            bf16x8 b0 = *(const bf16x8*)(bb + ln * 32);
            bf16x8 b1 = *(const bf16x8*)(bb + (16 + ln) * 32);
            acc0 = __builtin_amdgcn_mfma_f32_16x16x32_bf16(araw, b0, acc0, 0, 0, 0);
            acc1 = __builtin_amdgcn_mfma_f32_16x16x32_bf16(araw, b1, acc1, 0, 0, 0);
        }
        float* dstArr = grp ? gcnp : xatt;
        #pragma unroll
        for (int r = 0; r < 4; ++r) {
            int row = mt * 16 + kq * 4 + r;
            float bias = grp ? (alpha * edge_b[row] * S3s[row])
                             : (att_b[row] * S3s[row]);
            dstArr[row * 25 + ln] = acc0[r] + bias;
            if (ln < 9) dstArr[row * 25 + 16 + ln] = acc1[r] + bias;
            if (!grp) {   // fold xmean: row-sum from accumulator registers
                float s = acc0[r] + ((ln < 9) ? acc1[r] : 0.0f);
                s += __shfl_xor(s, 1, 16);
                s += __shfl_xor(s, 2, 16);
                s += __shfl_xor(s, 4, 16);
                s += __shfl_xor(s, 8, 16);
                if (ln == 0) xmean[row] = (s + 25.0f * bias) * 0.04f;
            }
        }
    }
    __syncthreads();

    // ===== prefetch epilogue operands (float4 LDS reads; quad ownership) =====
    float4 g4 = {0.f, 0.f, 0.f, 0.f}, xa4 = {0.f, 0.f, 0.f, 0.f};
    if (t < 400) {
        g4  = *(const float4*)&gcnp[4 * t];
        xa4 = *(const float4*)&xatt[4 * t];
    }

    // ===== MLP stage B (parallel): h[i] = GELU(BN(cc1 @ xm)), 8 lanes per i =====
    if (t < 256) {
        int i = t >> 3, s = t & 7;
        float p = 0.0f;
        #pragma unroll
        for (int k = 0; k < 8; ++k)
            p += cc1_w[i * 64 + s + 8 * k] * xmean[s + 8 * k];
        p += __shfl_down(p, 4, 8);
        p += __shfl_down(p, 2, 8);
        p += __shfl_down(p, 1, 8);
        if (s == 0) {
            p += cc1_b[i];
            p = (p - bn_m[i]) * (bn_g[i] * rsqrtf(bn_v[i] + 1e-5f)) + bn_b[i];
            hbuf[i] = 0.5f * p * (1.0f + erff(p * 0.70710678118654752f));
        }
    }
    __syncthreads();

    // ===== MLP stage C (parallel): catt[c] = sigmoid(cc2 @ h), 4 lanes per c =====
    if (t < 256) {
        int cq = t >> 2, s = t & 3;
        float p = 0.0f;
        #pragma unroll
        for (int k = 0; k < 8; ++k)
            p += cc2_w[cq * 32 + s + 4 * k] * hbuf[s + 4 * k];
        p += __shfl_down(p, 2, 4);
        p += __shfl_down(p, 1, 4);
        if (s == 0) {
            float cv = fast_sigmoid(p + cc2_b[cq]);
            catt[cq] = cv;
            csct[cq] = cs_w[cq] * cv;
        }
    }
    __syncthreads();

    // ===== satt (t<200) overlapped with epilogue partials (t<400) =====
    float part[4];
    if (t < 400) {
        #pragma unroll
        for (int j = 0; j < 4; ++j) {
            int i = 4 * t + j;
            int cc = i / 25;
            part[j] = (&g4.x)[j] * catt[cc] + (&xq.x)[j];
        }
    }
    if (t < 200) {
        int v = t >> 3, s8 = t & 7;
        float p = 0.0f;
        #pragma unroll
        for (int k = 0; k < 8; ++k) {
            int cc = s8 + 8 * k;
            p += csct[cc] * gcnp[cc * 25 + v];
        }
        p += __shfl_down(p, 4, 8);
        p += __shfl_down(p, 2, 8);
        p += __shfl_down(p, 1, 8);
        if (s8 == 0) satt[v] = fast_sigmoid(p + cs_b[0]);
    }
    __syncthreads();

    // ===== out = part + xatt*satt (float4 global store) =====
    if (t < 400) {
        float4 o;
        #pragma unroll
        for (int j = 0; j < 4; ++j) {
            int i = 4 * t + j;
            int cc = i / 25, v = i - cc * 25;
            (&o.x)[j] = part[j] + (&xa4.x)[j] * satt[v];
        }
        *(float4*)&out[(size_t)b * 1600 + 4 * t] = o;
    }
}

extern "C" void kernel_launch(void* const* d_in, const int* in_sizes, int n_in,
                              void* d_out, int out_size, void* d_ws, size_t ws_size,
                              hipStream_t stream) {
    const float* x        = (const float*)d_in[0];
    const float* A_static = (const float*)d_in[1];
    const float* w1       = (const float*)d_in[2];
    const float* b1       = (const float*)d_in[3];
    const float* w2       = (const float*)d_in[4];
    const float* b2       = (const float*)d_in[5];
    const float* w3       = (const float*)d_in[6];
    const float* b3       = (const float*)d_in[7];
    const float* diff_w   = (const float*)d_in[8];
    const float* diff_b   = (const float*)d_in[9];
    const float* edge_w   = (const float*)d_in[10];
    const float* edge_b   = (const float*)d_in[11];
    const float* att_w    = (const float*)d_in[12];
    const float* att_b    = (const float*)d_in[13];
    const float* cc1_w    = (const float*)d_in[14];
    const float* cc1_b    = (const float*)d_in[15];
    const float* bn_g     = (const float*)d_in[16];
    const float* bn_b     = (const float*)d_in[17];
    const float* bn_m     = (const float*)d_in[18];
    const float* bn_v     = (const float*)d_in[19];
    const float* cc2_w    = (const float*)d_in[20];
    const float* cc2_b    = (const float*)d_in[21];
    const float* cs_w     = (const float*)d_in[22];
    const float* cs_b     = (const float*)d_in[23];
    const float* alpha    = (const float*)d_in[24];
    float* outp = (float*)d_out;

    cga_fused<<<NB, 512, 0, stream>>>(x, A_static, w1, b1, w2, b2, w3, b3,
                                      diff_w, diff_b, edge_w, edge_b,
                                      att_w, att_b, cc1_w, cc1_b,
                                      bn_g, bn_b, bn_m, bn_v,
                                      cc2_w, cc2_b, cs_w, cs_b, alpha, outp);
}